// Round 15
// baseline (378.526 us; speedup 1.0000x reference)
//
#include <hip/hip_runtime.h>
#include <cstdint>
#include <cstddef>

typedef unsigned short u16;
typedef __attribute__((ext_vector_type(8))) short s16x8;
typedef __attribute__((ext_vector_type(4))) float f32x4;

#define DEV __device__ __forceinline__

DEV float bf2f(short u){
  union { unsigned int i; float f; } v;
  v.i = ((unsigned int)(u16)u) << 16;
  return v.f;
}
DEV short f2bf(float f){
  union { float f; unsigned int i; } v; v.f = f;
  unsigned int u = v.i;
  u += 0x7fffu + ((u >> 16) & 1u);   // RNE
  return (short)(u >> 16);
}
DEV f32x4 f32x4_zero(){
  f32x4 z;
#pragma unroll
  for(int j=0;j<4;j++) z[j]=0.f;
  return z;
}
DEV f32x4 mfma16(s16x8 a, s16x8 b, f32x4 c){
  return __builtin_amdgcn_mfma_f32_16x16x32_bf16(a, b, c, 0, 0, 0);
}
DEV void bar_lds(){
  asm volatile("s_waitcnt lgkmcnt(0)" ::: "memory");
  __builtin_amdgcn_s_barrier();
}
// async global -> LDS, 16 B per lane; per-lane global src, lds dst = base + lane*16
DEV void gload16(const u16* g, u16* l){
  __builtin_amdgcn_global_load_lds(
      (const __attribute__((address_space(1))) unsigned int*)g,
      (__attribute__((address_space(3))) unsigned int*)l, 16, 0, 0);
}

// ---------------- problem constants ----------------
// B=4, Cin=512 (concat), H=W=64, P=9 taps, Cout=256, M = B*H*W = 16384
// Y-formulation: Y[pp, p*256+o] = xn_pad[pp] . W_p  (+ 288 off-conv cols)
// Padded pixel domain: 4*66*66 = 17424 rows, padded to 17536 = 137*128.
// N = 2304 (dcn) + 288 (off, 27 used) -> padded to 2688 = 21*128.
static constexpr size_t STATS_B     = 0;                        // float[1024]
static constexpr size_t OUT2_ACC_B  = 4096;                     // float[16384*256]
static constexpr size_t XN_PAD_B    = 16781312;                 // u16[17536*512]
static constexpr size_t OUT1N_PAD_B = 34738176;                 // u16[4*66*66*256]
static constexpr size_t ZERO_BYTES  = 43659264;
static constexpr size_t OUT1RAW_B   = 43659264;                 // u16[16384*256] (pre-BN, fully written)
static constexpr size_t PPIX_B      = 60436480;                 // int[16384*9*4]
static constexpr size_t PWGT_B      = 62795776;                 // float[16384*9*4]
static constexpr size_t Y_B         = 65155072;                 // u16[17536*2688]
static constexpr size_t WALL_B      = 159428608;                // u16[2688*512]
static constexpr size_t W2T_B       = 162181120;                // u16[256*2304]
// end ~163.4 MB

// ---------------- NCHW fp32 (concat) -> padded NHWC bf16 ----------------
__global__ void k_x_to_nhwc(const float* __restrict__ v, const float* __restrict__ vi,
                            u16* __restrict__ xn){
  __shared__ float tile[64][65];
  const int b = blockIdx.z, c0 = blockIdx.y*64, hw0 = blockIdx.x*64;
  const int h = hw0 >> 6;
  const float* src = (c0 < 256) ? (v  + ((size_t)b*256 + c0)      *4096)
                                : (vi + ((size_t)b*256 + (c0-256))*4096);
  const int t = threadIdx.x;
#pragma unroll
  for(int k=0;k<16;k++){
    int idx = t + k*256;
    int cl = idx >> 6, wl = idx & 63;
    tile[cl][wl] = src[(size_t)cl*4096 + hw0 + wl];
  }
  __syncthreads();
#pragma unroll
  for(int k=0;k<16;k++){
    int idx = t + k*256;
    int wl = idx >> 6, cl = idx & 63;
    xn[((size_t)(b*66 + h+1)*66 + wl+1)*512 + c0 + cl] = (u16)f2bf(tile[cl][wl]);
  }
}

// ---------------- combined weight repack: [2688][512] bf16 ----------------
__global__ void k_prep_wall(const float* __restrict__ wdcn, const float* __restrict__ woff,
                            u16* __restrict__ wt){
  int idx = blockIdx.x*256 + threadIdx.x;
  if(idx >= 2688*512) return;
  int n = idx >> 9, c = idx & 511;
  float val = 0.f;
  if(n < 2304){
    int p = n >> 8, o = n & 255;
    val = wdcn[(size_t)(o*512 + c)*9 + p];
  } else if(n < 2592){
    int q = n - 2304, p = q >> 5, nn = q & 31;
    if(nn < 27) val = woff[(size_t)(nn*512 + c)*9 + p];
  }
  wt[idx] = (u16)f2bf(val);
}
__global__ void k_prep_w2(const float* __restrict__ w, u16* __restrict__ wt){
  int idx = blockIdx.x*256 + threadIdx.x;
  if(idx >= 256*2304) return;
  int n = idx / 2304, k = idx % 2304;
  int t = k >> 8, c = k & 255;
  wt[idx] = (u16)f2bf(w[(size_t)(n*256 + c)*9 + t]);
}

// ---------------- dense GEMM: Y[17536][2688] = xn_pad[17536][512] x Wall^T ----------------
// 128x128 tile, BK=64, dbuf LDS, counted vmcnt(8). 3 n-tiles per block chained
// through ONE hot pipeline (24 phases; pass boundary = flush acc->Y + vmcnt(0)).
// XCD-aware: xcd owns mt = xcd (mod 8); (mt-group, n-group) iterate within.
// Linear grid 8*18*7 = 1008; ~5% no-op (mt>=137).
__global__ __launch_bounds__(256, 2) void k_gemm_big(
    const u16* __restrict__ A, const u16* __restrict__ wt, u16* __restrict__ Y){
  const int bid = blockIdx.x;
  const int xcd = bid & 7;
  const int j   = bid >> 3;               // 0..125
  const int mt  = xcd + 8*(j/7);
  const int ng  = j % 7;                  // n-group: tiles ng*3 .. ng*3+2
  if(mt >= 137) return;
  __shared__ short A_lds[2][8][128][8];   // 32 KB
  __shared__ short B_lds[2][8][128][8];   // 32 KB
  const int tid = threadIdx.x;
  const int lane = tid & 63, wid = tid >> 6;
  const int quad = lane >> 4, ln = lane & 15;
  const int wm = wid >> 1, wn = wid & 1;
  const int m0 = mt * 128;
  constexpr int NPH = 24;                 // 3 passes x 8 K-steps
  f32x4 acc[4][4];
#pragma unroll
  for(int mf=0;mf<4;mf++)
#pragma unroll
    for(int nf=0;nf<4;nf++) acc[mf][nf] = f32x4_zero();

  auto stage = [&](int p, int bi){        // 8 gload16 per wave (4 A + 4 B)
    const int n0 = (ng*3 + (p >> 3)) * 128;
    const int k0 = (p & 7) * 64;
#pragma unroll
    for(int i=0;i<4;i++){
      const int idx = wid*4 + i;          // 0..15
      const int s = idx >> 1, rh = (idx & 1)*64;
      gload16(A  + (size_t)(m0 + rh + lane)*512 + k0 + s*8, (u16*)&A_lds[bi][s][rh][0]);
      gload16(wt + (size_t)(n0 + rh + lane)*512 + k0 + s*8, (u16*)&B_lds[bi][s][rh][0]);
    }
  };
  auto compute = [&](int bi){             // 32 MFMA per wave
#pragma unroll
    for(int kk=0;kk<2;kk++){
      s16x8 af[4], bf[4];
#pragma unroll
      for(int mf=0;mf<4;mf++)
        af[mf] = *(const s16x8*)&A_lds[bi][kk*4+quad][wm*64 + mf*16 + ln][0];
#pragma unroll
      for(int nf=0;nf<4;nf++)
        bf[nf] = *(const s16x8*)&B_lds[bi][kk*4+quad][wn*64 + nf*16 + ln][0];
#pragma unroll
      for(int mf=0;mf<4;mf++)
#pragma unroll
        for(int nf=0;nf<4;nf++)
          acc[mf][nf] = mfma16(af[mf], bf[nf], acc[mf][nf]);
    }
  };
  auto flushY = [&](int pass){            // write pass's 128x128 tile, reset acc
    const int n0 = (ng*3 + pass) * 128;
#pragma unroll
    for(int mf=0;mf<4;mf++)
#pragma unroll
      for(int nf=0;nf<4;nf++){
        const int col = n0 + wn*64 + nf*16 + ln;
#pragma unroll
        for(int i=0;i<4;i++){
          const int row = m0 + wm*64 + mf*16 + quad*4 + i;
          Y[(size_t)row*2688 + col] = (u16)f2bf(acc[mf][nf][i]);
        }
        acc[mf][nf] = f32x4_zero();
      }
  };

  stage(0, 0);
  asm volatile("s_waitcnt vmcnt(0)" ::: "memory");
  __builtin_amdgcn_s_barrier();
  stage(1, 1);
  for(int p = 0; p < NPH; ++p){
    const int bi = p & 1;
    compute(bi);
    bar_lds();
    const bool boundary = (p & 7) == 7;
    if(boundary) flushY(p >> 3);          // Y-stores issued before the drain below
    if(p + 2 < NPH) stage(p + 2, bi);
    if(boundary || p + 2 >= NPH){
      asm volatile("s_waitcnt vmcnt(0)" ::: "memory");   // drain stores+loads (3x/block)
    } else {
      asm volatile("s_waitcnt vmcnt(8)" ::: "memory");   // stage(p+1) landed
    }
    __builtin_amdgcn_sched_barrier(0);
    __builtin_amdgcn_s_barrier();
  }
}

// ---------------- off-combine: 9-tap shifted sum of Y off-cols -> bilinear tables -------
__global__ __launch_bounds__(256) void k_off_combine(
    const u16* __restrict__ Y, const float* __restrict__ boff,
    int* __restrict__ ppix, float* __restrict__ pwgt){
  __shared__ float offs[64][32];
  const int t = threadIdx.x;
  const int b = blockIdx.x >> 6, h = blockIdx.x & 63;
  const int w = t >> 2, g = t & 3;
  float acc[8];
#pragma unroll
  for(int j=0;j<8;j++) acc[j] = 0.f;
  for(int p=0;p<9;p++){
    const int pp = (b*66 + h + p/3)*66 + (w + p%3);   // fixed 3x3 taps, padded coords
    s16x8 v = *(const s16x8*)(Y + (size_t)pp*2688 + 2304 + p*32 + g*8);
#pragma unroll
    for(int j=0;j<8;j++) acc[j] += bf2f(v[j]);
  }
#pragma unroll
  for(int j=0;j<8;j++) offs[w][g*8 + j] = acc[j];
  __syncthreads();
  for(int id = t; id < 576; id += 256){
    const int tp = id / 64, ww = id & 63;
    const int m = (b<<12) + (h<<6) + ww;
    float dy = offs[ww][2*tp]   + boff[2*tp];
    float dx = offs[ww][2*tp+1] + boff[2*tp+1];
    float mz = offs[ww][18+tp]  + boff[18+tp];
    float mk = 1.f / (1.f + expf(-mz));
    float ypos = (float)(h - 1 + tp/3) + dy;
    float xpos = (float)(ww - 1 + tp%3) + dx;
    float y0f = floorf(ypos), x0f = floorf(xpos);
    float ly = ypos - y0f, lx = xpos - x0f;
    int y0 = (int)y0f, x0 = (int)x0f;
    const int id4 = (m*9 + tp)*4;
#pragma unroll
    for(int k=0;k<4;k++){
      int ddy = k >> 1, ddx = k & 1;
      int yi = y0 + ddy, xi = x0 + ddx;
      // clamp into padded domain; border rows of Y are exact zeros
      int yc = yi < -1 ? -1 : (yi > 64 ? 64 : yi);
      int xc = xi < -1 ? -1 : (xi > 64 ? 64 : xi);
      float wk = (ddy ? ly : 1.f-ly) * (ddx ? lx : 1.f-lx) * mk;
      ppix[id4+k] = (b*66 + yc+1)*66 + xc+1;          // padded pixel index
      pwgt[id4+k] = wk;
    }
  }
}

// ---------------- bilinear combine + fused BN1 stats (bf16 out1raw) ----------------
// grid 256 (one (b,h) row), 512 threads = 8 waves x 8 pixels; lane owns 4 cols.
__global__ __launch_bounds__(512) void k_combine(
    const u16* __restrict__ Y, const int* __restrict__ ppix,
    const float* __restrict__ pwgt, u16* __restrict__ out1raw,
    float* __restrict__ sum1, float* __restrict__ sq1){
  __shared__ int   s_pp[64][9][4];
  __shared__ float s_wg[64][9][4];
  __shared__ float s_red[2][8][256];
  const int t = threadIdx.x;
  const int b = blockIdx.x >> 6, h = blockIdx.x & 63;
  const int m_row = (b<<12) + (h<<6);
  for(int id = t; id < 576; id += 512){
    const int mo = id / 9, tp = id - mo*9;
    const size_t i4 = ((size_t)(m_row + mo)*9 + tp)*4;
    int4   pp4 = *(const int4*)  (ppix + i4);
    float4 wg4 = *(const float4*)(pwgt + i4);
    s_pp[mo][tp][0] = pp4.x; s_pp[mo][tp][1] = pp4.y;
    s_pp[mo][tp][2] = pp4.z; s_pp[mo][tp][3] = pp4.w;
    s_wg[mo][tp][0] = wg4.x; s_wg[mo][tp][1] = wg4.y;
    s_wg[mo][tp][2] = wg4.z; s_wg[mo][tp][3] = wg4.w;
  }
  __syncthreads();
  const int wv = t >> 6, lane = t & 63;
  const int c0 = lane*4;
  const int pw0 = wv*8;
  float acc[8][4];
#pragma unroll
  for(int pw=0;pw<8;pw++)
#pragma unroll
    for(int j=0;j<4;j++) acc[pw][j] = 0.f;

  for(int tp = 0; tp < 9; ++tp){
    const int cb = tp*256 + c0;
#pragma unroll
    for(int pw=0;pw<8;pw++){
      const int px = pw0 + pw;
#pragma unroll
      for(int k=0;k<4;k++){
        const float wk = s_wg[px][tp][k];
        const int   pp = s_pp[px][tp][k];
        ushort4 v = *(const ushort4*)(Y + (size_t)pp*2688 + cb);
        acc[pw][0] = fmaf(wk, bf2f((short)v.x), acc[pw][0]);
        acc[pw][1] = fmaf(wk, bf2f((short)v.y), acc[pw][1]);
        acc[pw][2] = fmaf(wk, bf2f((short)v.z), acc[pw][2]);
        acc[pw][3] = fmaf(wk, bf2f((short)v.w), acc[pw][3]);
      }
    }
  }
  float ls[4] = {0.f,0.f,0.f,0.f}, lq[4] = {0.f,0.f,0.f,0.f};
#pragma unroll
  for(int pw=0;pw<8;pw++){
    ushort4 o4;
    o4.x = (u16)f2bf(acc[pw][0]); o4.y = (u16)f2bf(acc[pw][1]);
    o4.z = (u16)f2bf(acc[pw][2]); o4.w = (u16)f2bf(acc[pw][3]);
    *(ushort4*)(out1raw + (size_t)(m_row + pw0 + pw)*256 + c0) = o4;
#pragma unroll
    for(int j=0;j<4;j++){
      ls[j] += acc[pw][j];
      lq[j] = fmaf(acc[pw][j], acc[pw][j], lq[j]);
    }
  }
#pragma unroll
  for(int j=0;j<4;j++){
    s_red[0][wv][c0+j] = ls[j];
    s_red[1][wv][c0+j] = lq[j];
  }
  __syncthreads();
  if(t < 256){
    float S = 0.f, Q = 0.f;
#pragma unroll
    for(int w8=0;w8<8;w8++){ S += s_red[0][w8][t]; Q += s_red[1][w8][t]; }
    unsafeAtomicAdd(sum1 + t, S);
    unsafeAtomicAdd(sq1 + t, Q);
  }
}

// ---------------- BN1 + ReLU: bf16 out1raw -> padded bf16 NHWC ----------------
__global__ void k_bn1(const u16* __restrict__ raw, const float* __restrict__ sum,
                      const float* __restrict__ sq, const float* __restrict__ g,
                      const float* __restrict__ bt, u16* __restrict__ o){
  __shared__ float sc[256], sh[256];
  const int t = threadIdx.x;
  {
    float mean = sum[t] * (1.f/16384.f);
    float var  = sq[t] * (1.f/16384.f) - mean*mean;
    float rstd = rsqrtf(var + 1e-5f);
    float s = g[t] * rstd;
    sc[t] = s; sh[t] = bt[t] - mean*s;
  }
  __syncthreads();
  const int c4 = (t & 63) * 4;
  const float s0 = sc[c4], s1 = sc[c4+1], s2 = sc[c4+2], s3 = sc[c4+3];
  const float h0 = sh[c4], h1 = sh[c4+1], h2 = sh[c4+2], h3 = sh[c4+3];
#pragma unroll
  for(int k=0;k<4;k++){
    int m = blockIdx.x*16 + k*4 + (t>>6);
    int b = m >> 12, hh = (m >> 6) & 63, ww = m & 63;
    const ushort4 v = *(const ushort4*)(raw + (size_t)m*256 + c4);
    unsigned int lo = (unsigned int)(u16)f2bf(fmaxf(0.f, bf2f((short)v.x)*s0 + h0))
                    | ((unsigned int)(u16)f2bf(fmaxf(0.f, bf2f((short)v.y)*s1 + h1)) << 16);
    unsigned int hi = (unsigned int)(u16)f2bf(fmaxf(0.f, bf2f((short)v.z)*s2 + h2))
                    | ((unsigned int)(u16)f2bf(fmaxf(0.f, bf2f((short)v.w)*s3 + h3)) << 16);
    uint2 pr; pr.x = lo; pr.y = hi;
    *(uint2*)(o + ((size_t)(b*66 + hh+1)*66 + ww+1)*256 + c4) = pr;
  }
}

// ---------------- GEMM2: out2 = im2col(out1n_pad)[16384][2304] x W2T[256][2304]^T ------
// XCD-aware: linear grid 512; each XCD owns m-tiles {xcd, xcd+8, ...}.
__global__ __launch_bounds__(256, 2) void k_gemm2(
    const u16* __restrict__ a_pad, const u16* __restrict__ wt, float* __restrict__ outa){
  const int bid = blockIdx.x;
  const int xcd = bid & 7;
  const int j   = bid >> 3;               // 0..63
  const int mt  = xcd + 8*(j >> 2);       // 0..127
  const int rest = j & 3;
  const int nt  = rest & 1;
  const int kz  = rest >> 1;
  __shared__ short A_lds[2][8][128][8];   // 32 KB
  __shared__ short B_lds[2][8][128][8];   // 32 KB
  const int tid = threadIdx.x;
  const int lane = tid & 63, wid = tid >> 6;
  const int quad = lane >> 4, ln = lane & 15;
  const int wm = wid >> 1, wn = wid & 1;
  const int m0 = mt * 128;
  const int n0 = nt * 128;
  const int kbase = kz * 1152;
  const int b = m0 >> 12;
  const int h0 = (m0 & 4095) >> 6;
  constexpr int NPH = 18;
  f32x4 acc[4][4];
#pragma unroll
  for(int mf=0;mf<4;mf++)
#pragma unroll
    for(int nf=0;nf<4;nf++) acc[mf][nf] = f32x4_zero();

  auto stage = [&](int t, int bi){
    const int k0 = kbase + t*64;
    const int tp = k0 >> 8, cit = k0 & 255;
    const int ty = tp/3, tx = tp - ty*3;
#pragma unroll
    for(int i=0;i<4;i++){
      const int idx = wid*4 + i;
      const int s = idx >> 1, rh = (idx & 1)*64;
      const int hh = h0 + (rh >> 6) + ty;
      gload16(a_pad + ((size_t)(b*66 + hh)*66 + lane + tx)*256 + cit + s*8,
              (u16*)&A_lds[bi][s][rh][0]);
      gload16(wt + (size_t)(n0 + rh + lane)*2304 + k0 + s*8,
              (u16*)&B_lds[bi][s][rh][0]);
    }
  };
  auto compute = [&](int bi){
#pragma unroll
    for(int kk=0;kk<2;kk++){
      s16x8 af[4], bf[4];
#pragma unroll
      for(int mf=0;mf<4;mf++)
        af[mf] = *(const s16x8*)&A_lds[bi][kk*4+quad][wm*64 + mf*16 + ln][0];
#pragma unroll
      for(int nf=0;nf<4;nf++)
        bf[nf] = *(const s16x8*)&B_lds[bi][kk*4+quad][wn*64 + nf*16 + ln][0];
#pragma unroll
      for(int mf=0;mf<4;mf++)
#pragma unroll
        for(int nf=0;nf<4;nf++)
          acc[mf][nf] = mfma16(af[mf], bf[nf], acc[mf][nf]);
    }
  };

  stage(0, 0);
  asm volatile("s_waitcnt vmcnt(0)" ::: "memory");
  __builtin_amdgcn_s_barrier();
  stage(1, 1);
  for(int t = 0; t < NPH; ++t){
    const int bi = t & 1;
    compute(bi);
    bar_lds();
    if(t + 2 < NPH){
      stage(t + 2, bi);
      asm volatile("s_waitcnt vmcnt(8)" ::: "memory");
    } else {
      asm volatile("s_waitcnt vmcnt(0)" ::: "memory");
    }
    __builtin_amdgcn_sched_barrier(0);
    __builtin_amdgcn_s_barrier();
  }

#pragma unroll
  for(int mf=0;mf<4;mf++)
#pragma unroll
    for(int nf=0;nf<4;nf++){
      const int col = n0 + wn*64 + nf*16 + ln;
#pragma unroll
      for(int i=0;i<4;i++){
        const int row = m0 + wm*64 + mf*16 + quad*4 + i;
        unsafeAtomicAdd(outa + (size_t)row*256 + col, acc[mf][nf][i]);
      }
    }
}

// ---------------- BN stats: per-channel sum/sumsq over M=16384 ----------------
__global__ void k_stats(const float* __restrict__ acc, float* __restrict__ sum,
                        float* __restrict__ sq){
  const int m0 = blockIdx.x*64;
  const int c = threadIdx.x;
  float s = 0.f, q = 0.f;
  for(int i=0;i<64;i++){
    float v = acc[(size_t)(m0+i)*256 + c];
    s += v; q += v*v;
  }
  unsafeAtomicAdd(sum + c, s);
  unsafeAtomicAdd(sq + c, q);
}

// ---------------- BN2 + ReLU + NHWC->NCHW fp32 output ----------------
__global__ void k_bn2_out(const float* __restrict__ acc, const float* __restrict__ sum,
                          const float* __restrict__ sq, const float* __restrict__ g,
                          const float* __restrict__ bt, float* __restrict__ out){
  __shared__ float tile[64][65];
  __shared__ float sc[64], sh[64];
  const int t = threadIdx.x;
  const int b = blockIdx.z, c0 = blockIdx.y*64, hw0 = blockIdx.x*64;
  if(t < 64){
    int c = c0 + t;
    float mean = sum[c] * (1.f/16384.f);
    float var  = sq[c] * (1.f/16384.f) - mean*mean;
    float rstd = rsqrtf(var + 1e-5f);
    float s = g[c] * rstd;
    sc[t] = s; sh[t] = bt[c] - mean*s;
  }
  __syncthreads();
#pragma unroll
  for(int k=0;k<16;k++){
    int idx = t + k*256;
    int wl = idx >> 6, cl = idx & 63;
    float v = acc[(size_t)((b<<12) + hw0 + wl)*256 + c0 + cl];
    tile[wl][cl] = fmaxf(0.f, v*sc[cl] + sh[cl]);
  }
  __syncthreads();
#pragma unroll
  for(int k=0;k<16;k++){
    int idx = t + k*256;
    int cl = idx >> 6, wl = idx & 63;
    out[(size_t)(b*256 + c0 + cl)*4096 + hw0 + wl] = tile[wl][cl];
  }
}

extern "C" void kernel_launch(void* const* d_in, const int* in_sizes, int n_in,
                              void* d_out, int out_size, void* d_ws, size_t ws_size,
                              hipStream_t stream){
  const float* in_v  = (const float*)d_in[0];
  const float* in_i  = (const float*)d_in[1];
  const float* w_off = (const float*)d_in[2];
  const float* b_off = (const float*)d_in[3];
  const float* w_dcn = (const float*)d_in[4];
  const float* g1    = (const float*)d_in[5];
  const float* bt1   = (const float*)d_in[6];
  const float* w2    = (const float*)d_in[7];
  const float* g2    = (const float*)d_in[8];
  const float* bt2   = (const float*)d_in[9];
  float* out = (float*)d_out;
  char* ws = (char*)d_ws;

  float* stats     = (float*)(ws + STATS_B);
  float* out2_acc  = (float*)(ws + OUT2_ACC_B);
  u16*   xn_pad    = (u16*)  (ws + XN_PAD_B);
  u16*   out1n_pad = (u16*)  (ws + OUT1N_PAD_B);
  u16*   out1raw   = (u16*)  (ws + OUT1RAW_B);
  int*   ppix      = (int*)  (ws + PPIX_B);
  float* pwgt      = (float*)(ws + PWGT_B);
  u16*   Ymat      = (u16*)  (ws + Y_B);
  u16*   wall      = (u16*)  (ws + WALL_B);
  u16*   w2t       = (u16*)  (ws + W2T_B);
  float* sum1 = stats,       *sq1 = stats + 256;
  float* sum2 = stats + 512, *sq2 = stats + 768;

  hipMemsetAsync(ws, 0, ZERO_BYTES, stream);
  k_x_to_nhwc<<<dim3(64,8,4), 256, 0, stream>>>(in_v, in_i, xn_pad);
  k_prep_wall<<<5376, 256, 0, stream>>>(w_dcn, w_off, wall);
  k_prep_w2<<<2304, 256, 0, stream>>>(w2, w2t);
  k_gemm_big<<<1008, 256, 0, stream>>>(xn_pad, wall, Ymat);
  k_off_combine<<<256, 256, 0, stream>>>(Ymat, b_off, ppix, pwgt);
  k_combine<<<256, 512, 0, stream>>>(Ymat, ppix, pwgt, out1raw, sum1, sq1);
  k_bn1<<<1024, 256, 0, stream>>>(out1raw, sum1, sq1, g1, bt1, out1n_pad);
  k_gemm2<<<512, 256, 0, stream>>>(out1n_pad, w2t, out2_acc);
  k_stats<<<256, 256, 0, stream>>>(out2_acc, sum2, sq2);
  k_bn2_out<<<dim3(64,4,4), 256, 0, stream>>>(out2_acc, sum2, sq2, g2, bt2, out);
}

// Round 16
// 352.250 us; speedup vs baseline: 1.0746x; 1.0746x over previous
//
#include <hip/hip_runtime.h>
#include <cstdint>
#include <cstddef>

typedef unsigned short u16;
typedef __attribute__((ext_vector_type(8))) short s16x8;
typedef __attribute__((ext_vector_type(4))) float f32x4;

#define DEV __device__ __forceinline__

DEV float bf2f(short u){
  union { unsigned int i; float f; } v;
  v.i = ((unsigned int)(u16)u) << 16;
  return v.f;
}
DEV short f2bf(float f){
  union { float f; unsigned int i; } v; v.f = f;
  unsigned int u = v.i;
  u += 0x7fffu + ((u >> 16) & 1u);   // RNE
  return (short)(u >> 16);
}
DEV f32x4 f32x4_zero(){
  f32x4 z;
#pragma unroll
  for(int j=0;j<4;j++) z[j]=0.f;
  return z;
}
DEV f32x4 mfma16(s16x8 a, s16x8 b, f32x4 c){
  return __builtin_amdgcn_mfma_f32_16x16x32_bf16(a, b, c, 0, 0, 0);
}
DEV void bar_lds(){
  asm volatile("s_waitcnt lgkmcnt(0)" ::: "memory");
  __builtin_amdgcn_s_barrier();
}
// async global -> LDS, 16 B per lane; per-lane global src, lds dst = base + lane*16
DEV void gload16(const u16* g, u16* l){
  __builtin_amdgcn_global_load_lds(
      (const __attribute__((address_space(1))) unsigned int*)g,
      (__attribute__((address_space(3))) unsigned int*)l, 16, 0, 0);
}

// ---------------- problem constants ----------------
// B=4, Cin=512 (concat), H=W=64, P=9 taps, Cout=256, M = B*H*W = 16384
// Y-formulation: Y[pp, p*256+o] = xn_pad[pp] . W_p  (+ 288 off-conv cols)
// Padded pixel domain: 4*66*66 = 17424 rows, padded to 17536 = 137*128.
// N = 2304 (dcn) + 288 (off, 27 used) -> padded to 2688 = 21*128.
static constexpr size_t STATS_B     = 0;                        // float[1024]
static constexpr size_t OUT2_ACC_B  = 4096;                     // float[16384*256]
static constexpr size_t XN_PAD_B    = 16781312;                 // u16[17536*512]
static constexpr size_t OUT1N_PAD_B = 34738176;                 // u16[4*66*66*256]
static constexpr size_t ZERO_BYTES  = 43659264;
static constexpr size_t OUT1_ACC_B  = 43659264;                 // float[16384*256] (fully written)
static constexpr size_t PPIX_B      = 60436480;                 // int[16384*9*4]
static constexpr size_t PWGT_B      = 62795776;                 // float[16384*9*4]
static constexpr size_t Y_B         = 65155072;                 // u16[17536*2688]
static constexpr size_t WALL_B      = 159428608;                // u16[2688*512]
static constexpr size_t W2T_B       = 162181120;                // u16[256*2304]
// end ~163.4 MB

// ---------------- NCHW fp32 (concat) -> padded NHWC bf16 ----------------
__global__ void k_x_to_nhwc(const float* __restrict__ v, const float* __restrict__ vi,
                            u16* __restrict__ xn){
  __shared__ float tile[64][65];
  const int b = blockIdx.z, c0 = blockIdx.y*64, hw0 = blockIdx.x*64;
  const int h = hw0 >> 6;
  const float* src = (c0 < 256) ? (v  + ((size_t)b*256 + c0)      *4096)
                                : (vi + ((size_t)b*256 + (c0-256))*4096);
  const int t = threadIdx.x;
#pragma unroll
  for(int k=0;k<16;k++){
    int idx = t + k*256;
    int cl = idx >> 6, wl = idx & 63;
    tile[cl][wl] = src[(size_t)cl*4096 + hw0 + wl];
  }
  __syncthreads();
#pragma unroll
  for(int k=0;k<16;k++){
    int idx = t + k*256;
    int wl = idx >> 6, cl = idx & 63;
    xn[((size_t)(b*66 + h+1)*66 + wl+1)*512 + c0 + cl] = (u16)f2bf(tile[cl][wl]);
  }
}

// ---------------- combined weight repack: [2688][512] bf16 ----------------
__global__ void k_prep_wall(const float* __restrict__ wdcn, const float* __restrict__ woff,
                            u16* __restrict__ wt){
  int idx = blockIdx.x*256 + threadIdx.x;
  if(idx >= 2688*512) return;
  int n = idx >> 9, c = idx & 511;
  float val = 0.f;
  if(n < 2304){
    int p = n >> 8, o = n & 255;
    val = wdcn[(size_t)(o*512 + c)*9 + p];
  } else if(n < 2592){
    int q = n - 2304, p = q >> 5, nn = q & 31;
    if(nn < 27) val = woff[(size_t)(nn*512 + c)*9 + p];
  }
  wt[idx] = (u16)f2bf(val);
}
__global__ void k_prep_w2(const float* __restrict__ w, u16* __restrict__ wt){
  int idx = blockIdx.x*256 + threadIdx.x;
  if(idx >= 256*2304) return;
  int n = idx / 2304, k = idx % 2304;
  int t = k >> 8, c = k & 255;
  wt[idx] = (u16)f2bf(w[(size_t)(n*256 + c)*9 + t]);
}

// ---------------- dense GEMM: Y[17536][2688] = xn_pad[17536][512] x Wall^T ----------------
// 128x128 tile, BK=64, dbuf LDS, counted vmcnt(8). 3 n-tiles per block chained
// through ONE hot pipeline (24 phases; pass boundary = flush acc->Y + vmcnt(0)).
// XCD-aware: xcd owns mt = xcd (mod 8); (mt-group, n-group) iterate within.
// Linear grid 8*18*7 = 1008; ~5% no-op (mt>=137).
__global__ __launch_bounds__(256, 2) void k_gemm_big(
    const u16* __restrict__ A, const u16* __restrict__ wt, u16* __restrict__ Y){
  const int bid = blockIdx.x;
  const int xcd = bid & 7;
  const int j   = bid >> 3;               // 0..125
  const int mt  = xcd + 8*(j/7);
  const int ng  = j % 7;                  // n-group: tiles ng*3 .. ng*3+2
  if(mt >= 137) return;
  __shared__ short A_lds[2][8][128][8];   // 32 KB
  __shared__ short B_lds[2][8][128][8];   // 32 KB
  const int tid = threadIdx.x;
  const int lane = tid & 63, wid = tid >> 6;
  const int quad = lane >> 4, ln = lane & 15;
  const int wm = wid >> 1, wn = wid & 1;
  const int m0 = mt * 128;
  constexpr int NPH = 24;                 // 3 passes x 8 K-steps
  f32x4 acc[4][4];
#pragma unroll
  for(int mf=0;mf<4;mf++)
#pragma unroll
    for(int nf=0;nf<4;nf++) acc[mf][nf] = f32x4_zero();

  auto stage = [&](int p, int bi){        // 8 gload16 per wave (4 A + 4 B)
    const int n0 = (ng*3 + (p >> 3)) * 128;
    const int k0 = (p & 7) * 64;
#pragma unroll
    for(int i=0;i<4;i++){
      const int idx = wid*4 + i;          // 0..15
      const int s = idx >> 1, rh = (idx & 1)*64;
      gload16(A  + (size_t)(m0 + rh + lane)*512 + k0 + s*8, (u16*)&A_lds[bi][s][rh][0]);
      gload16(wt + (size_t)(n0 + rh + lane)*512 + k0 + s*8, (u16*)&B_lds[bi][s][rh][0]);
    }
  };
  auto compute = [&](int bi){             // 32 MFMA per wave
#pragma unroll
    for(int kk=0;kk<2;kk++){
      s16x8 af[4], bf[4];
#pragma unroll
      for(int mf=0;mf<4;mf++)
        af[mf] = *(const s16x8*)&A_lds[bi][kk*4+quad][wm*64 + mf*16 + ln][0];
#pragma unroll
      for(int nf=0;nf<4;nf++)
        bf[nf] = *(const s16x8*)&B_lds[bi][kk*4+quad][wn*64 + nf*16 + ln][0];
#pragma unroll
      for(int mf=0;mf<4;mf++)
#pragma unroll
        for(int nf=0;nf<4;nf++)
          acc[mf][nf] = mfma16(af[mf], bf[nf], acc[mf][nf]);
    }
  };
  auto flushY = [&](int pass){            // write pass's 128x128 tile, reset acc
    const int n0 = (ng*3 + pass) * 128;
#pragma unroll
    for(int mf=0;mf<4;mf++)
#pragma unroll
      for(int nf=0;nf<4;nf++){
        const int col = n0 + wn*64 + nf*16 + ln;
#pragma unroll
        for(int i=0;i<4;i++){
          const int row = m0 + wm*64 + mf*16 + quad*4 + i;
          Y[(size_t)row*2688 + col] = (u16)f2bf(acc[mf][nf][i]);
        }
        acc[mf][nf] = f32x4_zero();
      }
  };

  stage(0, 0);
  asm volatile("s_waitcnt vmcnt(0)" ::: "memory");
  __builtin_amdgcn_s_barrier();
  stage(1, 1);
  for(int p = 0; p < NPH; ++p){
    const int bi = p & 1;
    compute(bi);
    bar_lds();
    const bool boundary = (p & 7) == 7;
    if(boundary) flushY(p >> 3);          // Y-stores issued before the drain below
    if(p + 2 < NPH) stage(p + 2, bi);
    if(boundary || p + 2 >= NPH){
      asm volatile("s_waitcnt vmcnt(0)" ::: "memory");   // drain stores+loads (3x/block)
    } else {
      asm volatile("s_waitcnt vmcnt(8)" ::: "memory");   // stage(p+1) landed
    }
    __builtin_amdgcn_sched_barrier(0);
    __builtin_amdgcn_s_barrier();
  }
}

// ---------------- off-combine: 9-tap shifted sum of Y off-cols -> bilinear tables -------
__global__ __launch_bounds__(256) void k_off_combine(
    const u16* __restrict__ Y, const float* __restrict__ boff,
    int* __restrict__ ppix, float* __restrict__ pwgt){
  __shared__ float offs[64][32];
  const int t = threadIdx.x;
  const int b = blockIdx.x >> 6, h = blockIdx.x & 63;
  const int w = t >> 2, g = t & 3;
  float acc[8];
#pragma unroll
  for(int j=0;j<8;j++) acc[j] = 0.f;
  for(int p=0;p<9;p++){
    const int pp = (b*66 + h + p/3)*66 + (w + p%3);   // fixed 3x3 taps, padded coords
    s16x8 v = *(const s16x8*)(Y + (size_t)pp*2688 + 2304 + p*32 + g*8);
#pragma unroll
    for(int j=0;j<8;j++) acc[j] += bf2f(v[j]);
  }
#pragma unroll
  for(int j=0;j<8;j++) offs[w][g*8 + j] = acc[j];
  __syncthreads();
  for(int id = t; id < 576; id += 256){
    const int tp = id / 64, ww = id & 63;
    const int m = (b<<12) + (h<<6) + ww;
    float dy = offs[ww][2*tp]   + boff[2*tp];
    float dx = offs[ww][2*tp+1] + boff[2*tp+1];
    float mz = offs[ww][18+tp]  + boff[18+tp];
    float mk = 1.f / (1.f + expf(-mz));
    float ypos = (float)(h - 1 + tp/3) + dy;
    float xpos = (float)(ww - 1 + tp%3) + dx;
    float y0f = floorf(ypos), x0f = floorf(xpos);
    float ly = ypos - y0f, lx = xpos - x0f;
    int y0 = (int)y0f, x0 = (int)x0f;
    const int id4 = (m*9 + tp)*4;
#pragma unroll
    for(int k=0;k<4;k++){
      int ddy = k >> 1, ddx = k & 1;
      int yi = y0 + ddy, xi = x0 + ddx;
      // clamp into padded domain; border rows of Y are exact zeros
      int yc = yi < -1 ? -1 : (yi > 64 ? 64 : yi);
      int xc = xi < -1 ? -1 : (xi > 64 ? 64 : xi);
      float wk = (ddy ? ly : 1.f-ly) * (ddx ? lx : 1.f-lx) * mk;
      ppix[id4+k] = (b*66 + yc+1)*66 + xc+1;          // padded pixel index
      pwgt[id4+k] = wk;
    }
  }
}

// ---------------- bilinear combine + fused BN1 stats ----------------
// grid 256 (one (b,h) row), 512 threads = 8 waves x 8 pixels; lane owns 4 cols.
// Block owns full 64 rows x 256 cols of out1 -> per-column sum/sumsq reduced in
// LDS and atomically added once per column per block (deletes the k_stats1 pass).
__global__ __launch_bounds__(512) void k_combine(
    const u16* __restrict__ Y, const int* __restrict__ ppix,
    const float* __restrict__ pwgt, float* __restrict__ out1,
    float* __restrict__ sum1, float* __restrict__ sq1){
  __shared__ int   s_pp[64][9][4];
  __shared__ float s_wg[64][9][4];
  __shared__ float s_red[2][8][256];
  const int t = threadIdx.x;
  const int b = blockIdx.x >> 6, h = blockIdx.x & 63;
  const int m_row = (b<<12) + (h<<6);
  for(int id = t; id < 576; id += 512){
    const int mo = id / 9, tp = id - mo*9;
    const size_t i4 = ((size_t)(m_row + mo)*9 + tp)*4;
    int4   pp4 = *(const int4*)  (ppix + i4);
    float4 wg4 = *(const float4*)(pwgt + i4);
    s_pp[mo][tp][0] = pp4.x; s_pp[mo][tp][1] = pp4.y;
    s_pp[mo][tp][2] = pp4.z; s_pp[mo][tp][3] = pp4.w;
    s_wg[mo][tp][0] = wg4.x; s_wg[mo][tp][1] = wg4.y;
    s_wg[mo][tp][2] = wg4.z; s_wg[mo][tp][3] = wg4.w;
  }
  __syncthreads();
  const int wv = t >> 6, lane = t & 63;
  const int c0 = lane*4;
  const int pw0 = wv*8;
  float acc[8][4];
#pragma unroll
  for(int pw=0;pw<8;pw++)
#pragma unroll
    for(int j=0;j<4;j++) acc[pw][j] = 0.f;

  for(int tp = 0; tp < 9; ++tp){
    const int cb = tp*256 + c0;
#pragma unroll
    for(int pw=0;pw<8;pw++){
      const int px = pw0 + pw;
#pragma unroll
      for(int k=0;k<4;k++){
        const float wk = s_wg[px][tp][k];
        const int   pp = s_pp[px][tp][k];
        ushort4 v = *(const ushort4*)(Y + (size_t)pp*2688 + cb);
        acc[pw][0] = fmaf(wk, bf2f((short)v.x), acc[pw][0]);
        acc[pw][1] = fmaf(wk, bf2f((short)v.y), acc[pw][1]);
        acc[pw][2] = fmaf(wk, bf2f((short)v.z), acc[pw][2]);
        acc[pw][3] = fmaf(wk, bf2f((short)v.w), acc[pw][3]);
      }
    }
  }
  float ls[4] = {0.f,0.f,0.f,0.f}, lq[4] = {0.f,0.f,0.f,0.f};
#pragma unroll
  for(int pw=0;pw<8;pw++){
    float4 o4;
    o4.x = acc[pw][0]; o4.y = acc[pw][1]; o4.z = acc[pw][2]; o4.w = acc[pw][3];
    *(float4*)(out1 + (size_t)(m_row + pw0 + pw)*256 + c0) = o4;
#pragma unroll
    for(int j=0;j<4;j++){
      ls[j] += acc[pw][j];
      lq[j] = fmaf(acc[pw][j], acc[pw][j], lq[j]);
    }
  }
#pragma unroll
  for(int j=0;j<4;j++){
    s_red[0][wv][c0+j] = ls[j];
    s_red[1][wv][c0+j] = lq[j];
  }
  __syncthreads();
  if(t < 256){
    float S = 0.f, Q = 0.f;
#pragma unroll
    for(int w8=0;w8<8;w8++){ S += s_red[0][w8][t]; Q += s_red[1][w8][t]; }
    unsafeAtomicAdd(sum1 + t, S);
    unsafeAtomicAdd(sq1 + t, Q);
  }
}

// ---------------- GEMM2: out2 = im2col(out1n_pad)[16384][2304] x W2T[256][2304]^T ------
// XCD-aware: linear grid 512; each XCD owns m-tiles {xcd, xcd+8, ...}.
__global__ __launch_bounds__(256, 2) void k_gemm2(
    const u16* __restrict__ a_pad, const u16* __restrict__ wt, float* __restrict__ outa){
  const int bid = blockIdx.x;
  const int xcd = bid & 7;
  const int j   = bid >> 3;               // 0..63
  const int mt  = xcd + 8*(j >> 2);       // 0..127
  const int rest = j & 3;
  const int nt  = rest & 1;
  const int kz  = rest >> 1;
  __shared__ short A_lds[2][8][128][8];   // 32 KB
  __shared__ short B_lds[2][8][128][8];   // 32 KB
  const int tid = threadIdx.x;
  const int lane = tid & 63, wid = tid >> 6;
  const int quad = lane >> 4, ln = lane & 15;
  const int wm = wid >> 1, wn = wid & 1;
  const int m0 = mt * 128;
  const int n0 = nt * 128;
  const int kbase = kz * 1152;
  const int b = m0 >> 12;
  const int h0 = (m0 & 4095) >> 6;
  constexpr int NPH = 18;
  f32x4 acc[4][4];
#pragma unroll
  for(int mf=0;mf<4;mf++)
#pragma unroll
    for(int nf=0;nf<4;nf++) acc[mf][nf] = f32x4_zero();

  auto stage = [&](int t, int bi){
    const int k0 = kbase + t*64;
    const int tp = k0 >> 8, cit = k0 & 255;
    const int ty = tp/3, tx = tp - ty*3;
#pragma unroll
    for(int i=0;i<4;i++){
      const int idx = wid*4 + i;
      const int s = idx >> 1, rh = (idx & 1)*64;
      const int hh = h0 + (rh >> 6) + ty;
      gload16(a_pad + ((size_t)(b*66 + hh)*66 + lane + tx)*256 + cit + s*8,
              (u16*)&A_lds[bi][s][rh][0]);
      gload16(wt + (size_t)(n0 + rh + lane)*2304 + k0 + s*8,
              (u16*)&B_lds[bi][s][rh][0]);
    }
  };
  auto compute = [&](int bi){
#pragma unroll
    for(int kk=0;kk<2;kk++){
      s16x8 af[4], bf[4];
#pragma unroll
      for(int mf=0;mf<4;mf++)
        af[mf] = *(const s16x8*)&A_lds[bi][kk*4+quad][wm*64 + mf*16 + ln][0];
#pragma unroll
      for(int nf=0;nf<4;nf++)
        bf[nf] = *(const s16x8*)&B_lds[bi][kk*4+quad][wn*64 + nf*16 + ln][0];
#pragma unroll
      for(int mf=0;mf<4;mf++)
#pragma unroll
        for(int nf=0;nf<4;nf++)
          acc[mf][nf] = mfma16(af[mf], bf[nf], acc[mf][nf]);
    }
  };

  stage(0, 0);
  asm volatile("s_waitcnt vmcnt(0)" ::: "memory");
  __builtin_amdgcn_s_barrier();
  stage(1, 1);
  for(int t = 0; t < NPH; ++t){
    const int bi = t & 1;
    compute(bi);
    bar_lds();
    if(t + 2 < NPH){
      stage(t + 2, bi);
      asm volatile("s_waitcnt vmcnt(8)" ::: "memory");
    } else {
      asm volatile("s_waitcnt vmcnt(0)" ::: "memory");
    }
    __builtin_amdgcn_sched_barrier(0);
    __builtin_amdgcn_s_barrier();
  }

#pragma unroll
  for(int mf=0;mf<4;mf++)
#pragma unroll
    for(int nf=0;nf<4;nf++){
      const int col = n0 + wn*64 + nf*16 + ln;
#pragma unroll
      for(int i=0;i<4;i++){
        const int row = m0 + wm*64 + mf*16 + quad*4 + i;
        unsafeAtomicAdd(outa + (size_t)row*256 + col, acc[mf][nf][i]);
      }
    }
}

// ---------------- BN stats: per-channel sum/sumsq over M=16384 ----------------
__global__ void k_stats(const float* __restrict__ acc, float* __restrict__ sum,
                        float* __restrict__ sq){
  const int m0 = blockIdx.x*64;
  const int c = threadIdx.x;
  float s = 0.f, q = 0.f;
  for(int i=0;i<64;i++){
    float v = acc[(size_t)(m0+i)*256 + c];
    s += v; q += v*v;
  }
  unsafeAtomicAdd(sum + c, s);
  unsafeAtomicAdd(sq + c, q);
}

// ---------------- BN1 + ReLU -> padded bf16 NHWC ----------------
__global__ void k_bn1(const float* __restrict__ acc, const float* __restrict__ sum,
                      const float* __restrict__ sq, const float* __restrict__ g,
                      const float* __restrict__ bt, u16* __restrict__ o){
  __shared__ float sc[256], sh[256];
  const int t = threadIdx.x;
  {
    float mean = sum[t] * (1.f/16384.f);
    float var  = sq[t] * (1.f/16384.f) - mean*mean;
    float rstd = rsqrtf(var + 1e-5f);
    float s = g[t] * rstd;
    sc[t] = s; sh[t] = bt[t] - mean*s;
  }
  __syncthreads();
  const int c4 = (t & 63) * 4;
  const float s0 = sc[c4], s1 = sc[c4+1], s2 = sc[c4+2], s3 = sc[c4+3];
  const float h0 = sh[c4], h1 = sh[c4+1], h2 = sh[c4+2], h3 = sh[c4+3];
#pragma unroll
  for(int k=0;k<4;k++){
    int m = blockIdx.x*16 + k*4 + (t>>6);
    int b = m >> 12, hh = (m >> 6) & 63, ww = m & 63;
    const float4 v = *(const float4*)(acc + (size_t)m*256 + c4);
    unsigned int lo = (unsigned int)(u16)f2bf(fmaxf(0.f, v.x*s0 + h0))
                    | ((unsigned int)(u16)f2bf(fmaxf(0.f, v.y*s1 + h1)) << 16);
    unsigned int hi = (unsigned int)(u16)f2bf(fmaxf(0.f, v.z*s2 + h2))
                    | ((unsigned int)(u16)f2bf(fmaxf(0.f, v.w*s3 + h3)) << 16);
    uint2 pr; pr.x = lo; pr.y = hi;
    *(uint2*)(o + ((size_t)(b*66 + hh+1)*66 + ww+1)*256 + c4) = pr;
  }
}

// ---------------- BN2 + ReLU + NHWC->NCHW fp32 output ----------------
__global__ void k_bn2_out(const float* __restrict__ acc, const float* __restrict__ sum,
                          const float* __restrict__ sq, const float* __restrict__ g,
                          const float* __restrict__ bt, float* __restrict__ out){
  __shared__ float tile[64][65];
  __shared__ float sc[64], sh[64];
  const int t = threadIdx.x;
  const int b = blockIdx.z, c0 = blockIdx.y*64, hw0 = blockIdx.x*64;
  if(t < 64){
    int c = c0 + t;
    float mean = sum[c] * (1.f/16384.f);
    float var  = sq[c] * (1.f/16384.f) - mean*mean;
    float rstd = rsqrtf(var + 1e-5f);
    float s = g[c] * rstd;
    sc[t] = s; sh[t] = bt[c] - mean*s;
  }
  __syncthreads();
#pragma unroll
  for(int k=0;k<16;k++){
    int idx = t + k*256;
    int wl = idx >> 6, cl = idx & 63;
    float v = acc[(size_t)((b<<12) + hw0 + wl)*256 + c0 + cl];
    tile[wl][cl] = fmaxf(0.f, v*sc[cl] + sh[cl]);
  }
  __syncthreads();
#pragma unroll
  for(int k=0;k<16;k++){
    int idx = t + k*256;
    int cl = idx >> 6, wl = idx & 63;
    out[(size_t)(b*256 + c0 + cl)*4096 + hw0 + wl] = tile[wl][cl];
  }
}

extern "C" void kernel_launch(void* const* d_in, const int* in_sizes, int n_in,
                              void* d_out, int out_size, void* d_ws, size_t ws_size,
                              hipStream_t stream){
  const float* in_v  = (const float*)d_in[0];
  const float* in_i  = (const float*)d_in[1];
  const float* w_off = (const float*)d_in[2];
  const float* b_off = (const float*)d_in[3];
  const float* w_dcn = (const float*)d_in[4];
  const float* g1    = (const float*)d_in[5];
  const float* bt1   = (const float*)d_in[6];
  const float* w2    = (const float*)d_in[7];
  const float* g2    = (const float*)d_in[8];
  const float* bt2   = (const float*)d_in[9];
  float* out = (float*)d_out;
  char* ws = (char*)d_ws;

  float* stats     = (float*)(ws + STATS_B);
  float* out2_acc  = (float*)(ws + OUT2_ACC_B);
  u16*   xn_pad    = (u16*)  (ws + XN_PAD_B);
  u16*   out1n_pad = (u16*)  (ws + OUT1N_PAD_B);
  float* out1_acc  = (float*)(ws + OUT1_ACC_B);
  int*   ppix      = (int*)  (ws + PPIX_B);
  float* pwgt      = (float*)(ws + PWGT_B);
  u16*   Ymat      = (u16*)  (ws + Y_B);
  u16*   wall      = (u16*)  (ws + WALL_B);
  u16*   w2t       = (u16*)  (ws + W2T_B);
  float* sum1 = stats,       *sq1 = stats + 256;
  float* sum2 = stats + 512, *sq2 = stats + 768;

  hipMemsetAsync(ws, 0, ZERO_BYTES, stream);
  k_x_to_nhwc<<<dim3(64,8,4), 256, 0, stream>>>(in_v, in_i, xn_pad);
  k_prep_wall<<<5376, 256, 0, stream>>>(w_dcn, w_off, wall);
  k_prep_w2<<<2304, 256, 0, stream>>>(w2, w2t);
  k_gemm_big<<<1008, 256, 0, stream>>>(xn_pad, wall, Ymat);
  k_off_combine<<<256, 256, 0, stream>>>(Ymat, b_off, ppix, pwgt);
  k_combine<<<256, 512, 0, stream>>>(Ymat, ppix, pwgt, out1_acc, sum1, sq1);
  k_bn1<<<1024, 256, 0, stream>>>(out1_acc, sum1, sq1, g1, bt1, out1n_pad);
  k_gemm2<<<512, 256, 0, stream>>>(out1n_pad, w2t, out2_acc);
  k_stats<<<256, 256, 0, stream>>>(out2_acc, sum2, sq2);
  k_bn2_out<<<dim3(64,4,4), 256, 0, stream>>>(out2_acc, sum2, sq2, g2, bt2, out);
}